// Round 1
// baseline (222.944 us; speedup 1.0000x reference)
//
#include <hip/hip_runtime.h>

#define BB 8
#define CC 512
#define LL 2048
#define GG 4
#define CPG 128   // channels per group

typedef _Float16 f16;
typedef _Float16 f16x8 __attribute__((ext_vector_type(8)));
typedef float f32x4 __attribute__((ext_vector_type(4)));

// ---------------------------------------------------------------------------
// Weight conversion: fp32 -> f16, build [qw;kw] stack and [qb;kb] concat
// ---------------------------------------------------------------------------
__global__ __launch_bounds__(256) void convert_w(
    const float* __restrict__ qw, const float* __restrict__ kw,
    const float* __restrict__ vw, const float* __restrict__ pw,
    const float* __restrict__ qb, const float* __restrict__ kb,
    f16* __restrict__ Wqk, f16* __restrict__ Wv, f16* __restrict__ Wp,
    float* __restrict__ qkb)
{
    int i = blockIdx.x * 256 + threadIdx.x;
    if (i < CC * CC) {
        Wqk[i]           = (f16)qw[i];
        Wqk[CC * CC + i] = (f16)kw[i];
        Wv[i]            = (f16)vw[i];
        Wp[i]            = (f16)pw[i];
    }
    if (i < CC) { qkb[i] = qb[i]; qkb[CC + i] = kb[i]; }
}

// ---------------------------------------------------------------------------
// GroupNorm stage A: partial sums per (b, g, slice)
// grid (32, GG, BB), block 256. Each slice = 8192 floats.
// ---------------------------------------------------------------------------
__global__ __launch_bounds__(256) void gn_partial(
    const float* __restrict__ x, float2* __restrict__ part)
{
    int s = blockIdx.x, g = blockIdx.y, b = blockIdx.z;
    const float4* p = (const float4*)(x + (size_t)b * CC * LL + (size_t)g * CPG * LL
                                        + (size_t)s * 8192);
    float sum = 0.f, sq = 0.f;
    for (int i = threadIdx.x; i < 2048; i += 256) {
        float4 v = p[i];
        sum += v.x + v.y + v.z + v.w;
        sq  += v.x * v.x + v.y * v.y + v.z * v.z + v.w * v.w;
    }
    for (int o = 32; o; o >>= 1) { sum += __shfl_xor(sum, o); sq += __shfl_xor(sq, o); }
    __shared__ float2 red[4];
    int wave = threadIdx.x >> 6, lane = threadIdx.x & 63;
    if (lane == 0) red[wave] = make_float2(sum, sq);
    __syncthreads();
    if (threadIdx.x == 0) {
        float S = red[0].x + red[1].x + red[2].x + red[3].x;
        float Q = red[0].y + red[1].y + red[2].y + red[3].y;
        part[((size_t)b * GG + g) * 32 + s] = make_float2(S, Q);
    }
}

// GroupNorm stage B: 32 (b,g) groups -> mean, rstd
__global__ void gn_finalize(const float2* __restrict__ part, float2* __restrict__ stats)
{
    int t = threadIdx.x;
    if (t < BB * GG) {
        float s = 0.f, q = 0.f;
        for (int i = 0; i < 32; ++i) { float2 p = part[t * 32 + i]; s += p.x; q += p.y; }
        const float invN = 1.0f / (float)(CPG * LL);
        float mean = s * invN;
        float var  = q * invN - mean * mean;
        stats[t] = make_float2(mean, rsqrtf(var + 1e-6f));
    }
}

// GroupNorm normalize + affine + TRANSPOSE: x [C,L] fp32 -> xnT [L,C] f16
// grid (LL/64, CC/64, BB), block 256, LDS 64x65 floats
__global__ __launch_bounds__(256) void gn_norm_t(
    const float* __restrict__ x, const float2* __restrict__ stats,
    const float* __restrict__ gw, const float* __restrict__ gb,
    f16* __restrict__ xnT)
{
    __shared__ float t[64][65];
    int l0 = blockIdx.x * 64, c0 = blockIdx.y * 64, b = blockIdx.z;
    float2 st = stats[b * GG + (c0 >> 7)];
    const float* xb = x + (size_t)b * CC * LL;
    for (int i = threadIdx.x; i < 4096; i += 256) {
        int c = i >> 6, l = i & 63;
        float v = xb[(size_t)(c0 + c) * LL + l0 + l];
        t[c][l] = (v - st.x) * st.y * gw[c0 + c] + gb[c0 + c];
    }
    __syncthreads();
    f16* o = xnT + (size_t)b * LL * CC;
    for (int i = threadIdx.x; i < 4096; i += 256) {
        int l = i >> 6, c = i & 63;
        o[(size_t)(l0 + l) * CC + c0 + c] = (f16)t[c][l];
    }
}

// ---------------------------------------------------------------------------
// Generic batched GEMM  C[M,N] = alpha * A[M,K] · B[N,K]^T (+bias)(+resid)
// All operands K-contiguous f16. 128x128 tile, BK=64, 4 waves (2x2), 4x4 frags.
// XOR-swizzled LDS: physByte = (row*128 + colByte) ^ ((row&7)<<4).
// BIAS_MODE: 0 none, 1 bias[row], 2 bias[col]. RESID: += resid[row*ldc+col].
// ---------------------------------------------------------------------------
template<int BIAS_MODE, bool RESID, typename OUT_T>
__global__ __launch_bounds__(256) void gemm_bt(
    const f16* __restrict__ A, size_t sA,
    const f16* __restrict__ B, size_t sB,
    OUT_T* __restrict__ Co, size_t sC,
    const float* __restrict__ resid, size_t sR,
    const float* __restrict__ bias,
    int M, int N, int K, int lda, int ldb, int ldc, float alpha)
{
    const int tid  = threadIdx.x;
    const int lane = tid & 63;
    const int wave = tid >> 6;
    const int wr = wave >> 1, wc = wave & 1;
    const int l15 = lane & 15, lhi = lane >> 4;
    const int bm = blockIdx.y, bn = blockIdx.x, bz = blockIdx.z;

    A  += (size_t)bz * sA;
    B  += (size_t)bz * sB;
    Co += (size_t)bz * sC;

    __shared__ f16 ldsA[128 * 64];
    __shared__ f16 ldsB[128 * 64];

    f32x4 acc[4][4] = {};

    const int colE    = (tid & 7) * 8;     // element col within K-tile (fixed/thread)
    const int colByte = colE * 2;

    for (int k0 = 0; k0 < K; k0 += 64) {
#pragma unroll
        for (int it = 0; it < 4; ++it) {
            int row = (tid >> 3) + it * 32;
            f16x8 va = *(const f16x8*)(A + (size_t)(bm * 128 + row) * lda + k0 + colE);
            f16x8 vb = *(const f16x8*)(B + (size_t)(bn * 128 + row) * ldb + k0 + colE);
            int phys = ((row * 128 + colByte) ^ ((row & 7) << 4)) >> 1;
            *(f16x8*)(ldsA + phys) = va;
            *(f16x8*)(ldsB + phys) = vb;
        }
        __syncthreads();
#pragma unroll
        for (int kk = 0; kk < 64; kk += 32) {
            const int kb2 = (kk + lhi * 8) * 2;   // byte col of fragment
            f16x8 af[4], bfr[4];
#pragma unroll
            for (int m = 0; m < 4; ++m) {
                int row = wr * 64 + m * 16 + l15;
                int phys = ((row * 128 + kb2) ^ ((row & 7) << 4)) >> 1;
                af[m] = *(const f16x8*)(ldsA + phys);
            }
#pragma unroll
            for (int n = 0; n < 4; ++n) {
                int row = wc * 64 + n * 16 + l15;
                int phys = ((row * 128 + kb2) ^ ((row & 7) << 4)) >> 1;
                bfr[n] = *(const f16x8*)(ldsB + phys);
            }
#pragma unroll
            for (int m = 0; m < 4; ++m)
#pragma unroll
                for (int n = 0; n < 4; ++n)
                    acc[m][n] = __builtin_amdgcn_mfma_f32_16x16x32_f16(
                        af[m], bfr[n], acc[m][n], 0, 0, 0);
        }
        __syncthreads();
    }

#pragma unroll
    for (int m = 0; m < 4; ++m) {
#pragma unroll
        for (int n = 0; n < 4; ++n) {
            int col = bn * 128 + wc * 64 + n * 16 + l15;
#pragma unroll
            for (int r = 0; r < 4; ++r) {
                int row = bm * 128 + wr * 64 + m * 16 + lhi * 4 + r;
                float v = acc[m][n][r] * alpha;
                if (BIAS_MODE == 1) v += bias[row];
                if (BIAS_MODE == 2) v += bias[col];
                if (RESID) v += resid[(size_t)bz * sR + (size_t)row * ldc + col];
                Co[(size_t)row * ldc + col] = (OUT_T)v;
            }
        }
    }
}

// ---------------------------------------------------------------------------
// Row softmax in-place on f16 P [L, L] per (b, row). grid (LL, BB), block 256.
// ---------------------------------------------------------------------------
__global__ __launch_bounds__(256) void softmax_rows(f16* __restrict__ P)
{
    int i = blockIdx.x, b = blockIdx.y;
    f16* row = P + ((size_t)b * LL + (size_t)i) * LL;
    int tid = threadIdx.x;
    f16x8 v = ((const f16x8*)row)[tid];
    float f[8], mx = -1e30f;
#pragma unroll
    for (int j = 0; j < 8; ++j) { f[j] = (float)v[j]; mx = fmaxf(mx, f[j]); }
    for (int o = 32; o; o >>= 1) mx = fmaxf(mx, __shfl_xor(mx, o));
    __shared__ float red1[4];
    __shared__ float red2[4];
    int wave = tid >> 6, lane = tid & 63;
    if (lane == 0) red1[wave] = mx;
    __syncthreads();
    mx = fmaxf(fmaxf(red1[0], red1[1]), fmaxf(red1[2], red1[3]));
    float s = 0.f;
#pragma unroll
    for (int j = 0; j < 8; ++j) { f[j] = __expf(f[j] - mx); s += f[j]; }
    for (int o = 32; o; o >>= 1) s += __shfl_xor(s, o);
    if (lane == 0) red2[wave] = s;
    __syncthreads();
    s = red2[0] + red2[1] + red2[2] + red2[3];
    float inv = 1.0f / s;
    f16x8 o8;
#pragma unroll
    for (int j = 0; j < 8; ++j) o8[j] = (f16)(f[j] * inv);
    ((f16x8*)row)[tid] = o8;
}

// Fallback marker if workspace is too small (distinct absmax signal ~12345)
__global__ void fill_marker(float* out, int n)
{
    int i = blockIdx.x * 256 + threadIdx.x;
    if (i < n) out[i] = 12345.0f;
}

// ---------------------------------------------------------------------------
extern "C" void kernel_launch(void* const* d_in, const int* in_sizes, int n_in,
                              void* d_out, int out_size, void* d_ws, size_t ws_size,
                              hipStream_t stream)
{
    const float* x  = (const float*)d_in[0];
    const float* gw = (const float*)d_in[1];
    const float* gb = (const float*)d_in[2];
    const float* qw = (const float*)d_in[3];
    const float* qb = (const float*)d_in[4];
    const float* kw = (const float*)d_in[5];
    const float* kb = (const float*)d_in[6];
    const float* vw = (const float*)d_in[7];
    const float* vb = (const float*)d_in[8];
    const float* pw = (const float*)d_in[9];
    const float* pb = (const float*)d_in[10];
    float* out = (float*)d_out;

    // workspace layout (bytes)
    char* w = (char*)d_ws;
    float2* part  = (float2*)w;                       //   8 KB
    float2* stats = (float2*)(w + 8192);              //   256 B
    f16* Wqk  = (f16*)(w + 16384);                    //   1 MB   [1024,512]
    f16* Wv   = Wqk + (size_t)1024 * CC;              // 512 KB   [512,512]
    f16* Wp   = Wv  + (size_t)CC * CC;                // 512 KB
    float* qkb = (float*)(Wp + (size_t)CC * CC);      //   4 KB
    f16* xnT  = (f16*)((char*)qkb + 4096);            // 16 MB    [B][L,C]
    f16* QK   = xnT + (size_t)BB * LL * CC;           // 32 MB    [B][L,1024]
    f16* Vm   = QK  + (size_t)BB * LL * 1024;         // 16 MB    [B][C,L]
    f16* Pm   = Vm  + (size_t)BB * CC * LL;           // 64 MB    [B][L,L]
    f16* O2   = xnT;  // alias: xnT dead after gemm2  //          [B][L,C]
    size_t need = (size_t)((char*)(Pm + (size_t)BB * LL * LL) - w);
    if (ws_size < need) {
        fill_marker<<<(out_size + 255) / 256, 256, 0, stream>>>(out, out_size);
        return;
    }

    convert_w<<<dim3((CC * CC + 255) / 256), 256, 0, stream>>>(
        qw, kw, vw, pw, qb, kb, Wqk, Wv, Wp, qkb);
    gn_partial<<<dim3(32, GG, BB), 256, 0, stream>>>(x, part);
    gn_finalize<<<1, 64, 0, stream>>>(part, stats);
    gn_norm_t<<<dim3(LL / 64, CC / 64, BB), 256, 0, stream>>>(x, stats, gw, gb, xnT);

    // GEMM1: [Q|K]t[l, n] = xnT[l,:] . Wqk[n,:] + qkb[n]     (M=L, N=1024, K=C)
    gemm_bt<2, false, f16><<<dim3(1024 / 128, LL / 128, BB), 256, 0, stream>>>(
        xnT, (size_t)LL * CC, Wqk, 0, QK, (size_t)LL * 1024, nullptr, 0, qkb,
        LL, 1024, CC, CC, CC, 1024, 1.0f);

    // GEMM2: V[c, l] = Wv[c,:] . xnT[l,:] + vb[c]            (M=C, N=L, K=C)
    gemm_bt<1, false, f16><<<dim3(LL / 128, CC / 128, BB), 256, 0, stream>>>(
        Wv, 0, xnT, (size_t)LL * CC, Vm, (size_t)CC * LL, nullptr, 0, vb,
        CC, LL, CC, CC, CC, LL, 1.0f);

    // GEMM3: S[i, j] = scale * Qt[i,:] . Kt[j,:]             (M=L, N=L, K=C)
    gemm_bt<0, false, f16><<<dim3(LL / 128, LL / 128, BB), 256, 0, stream>>>(
        QK, (size_t)LL * 1024, QK + CC, (size_t)LL * 1024, Pm, (size_t)LL * LL,
        nullptr, 0, nullptr,
        LL, LL, CC, 1024, 1024, LL, 0.04419417382415922f);

    softmax_rows<<<dim3(LL, BB), 256, 0, stream>>>(Pm);

    // GEMM4: O2[i, c] = P[i,:] . V[c,:]                      (M=L, N=C, K=L)
    gemm_bt<0, false, f16><<<dim3(CC / 128, LL / 128, BB), 256, 0, stream>>>(
        Pm, (size_t)LL * LL, Vm, (size_t)CC * LL, O2, (size_t)LL * CC,
        nullptr, 0, nullptr,
        LL, CC, LL, LL, LL, CC, 1.0f);

    // GEMM5: out[c, l] = Wp[c,:] . O2[l,:] + pb[c] + x[c,l]  (M=C, N=L, K=C)
    gemm_bt<1, true, float><<<dim3(LL / 128, CC / 128, BB), 256, 0, stream>>>(
        Wp, 0, O2, (size_t)LL * CC, out, (size_t)CC * LL, x, (size_t)CC * LL, pb,
        CC, LL, CC, CC, CC, LL, 1.0f);
}

// Round 2
// 209.092 us; speedup vs baseline: 1.0662x; 1.0662x over previous
//
#include <hip/hip_runtime.h>

#define BB 8
#define CC 512
#define LL 2048
#define GG 4
#define CPG 128   // channels per group

typedef _Float16 f16;
typedef _Float16 f16x8 __attribute__((ext_vector_type(8)));
typedef float f32x4 __attribute__((ext_vector_type(4)));

__device__ __forceinline__ void gload_lds16(const f16* g, f16* l)
{
    __builtin_amdgcn_global_load_lds(
        (__attribute__((address_space(1))) void*)g,
        (__attribute__((address_space(3))) void*)l, 16, 0, 0);
}

// ---------------------------------------------------------------------------
// Weight conversion: fp32 -> f16, build [qw;kw] stack and [qb;kb] concat
// ---------------------------------------------------------------------------
__global__ __launch_bounds__(256) void convert_w(
    const float* __restrict__ qw, const float* __restrict__ kw,
    const float* __restrict__ vw, const float* __restrict__ pw,
    const float* __restrict__ qb, const float* __restrict__ kb,
    f16* __restrict__ Wqk, f16* __restrict__ Wv, f16* __restrict__ Wp,
    float* __restrict__ qkb)
{
    int i = blockIdx.x * 256 + threadIdx.x;
    if (i < CC * CC) {
        Wqk[i]           = (f16)qw[i];
        Wqk[CC * CC + i] = (f16)kw[i];
        Wv[i]            = (f16)vw[i];
        Wp[i]            = (f16)pw[i];
    }
    if (i < CC) { qkb[i] = qb[i]; qkb[CC + i] = kb[i]; }
}

// ---------------------------------------------------------------------------
// GroupNorm stage A: partial sums per (b, g, slice)
// ---------------------------------------------------------------------------
__global__ __launch_bounds__(256) void gn_partial(
    const float* __restrict__ x, float2* __restrict__ part)
{
    int s = blockIdx.x, g = blockIdx.y, b = blockIdx.z;
    const float4* p = (const float4*)(x + (size_t)b * CC * LL + (size_t)g * CPG * LL
                                        + (size_t)s * 8192);
    float sum = 0.f, sq = 0.f;
    for (int i = threadIdx.x; i < 2048; i += 256) {
        float4 v = p[i];
        sum += v.x + v.y + v.z + v.w;
        sq  += v.x * v.x + v.y * v.y + v.z * v.z + v.w * v.w;
    }
    for (int o = 32; o; o >>= 1) { sum += __shfl_xor(sum, o); sq += __shfl_xor(sq, o); }
    __shared__ float2 red[4];
    int wave = threadIdx.x >> 6, lane = threadIdx.x & 63;
    if (lane == 0) red[wave] = make_float2(sum, sq);
    __syncthreads();
    if (threadIdx.x == 0) {
        float S = red[0].x + red[1].x + red[2].x + red[3].x;
        float Q = red[0].y + red[1].y + red[2].y + red[3].y;
        part[((size_t)b * GG + g) * 32 + s] = make_float2(S, Q);
    }
}

__global__ void gn_finalize(const float2* __restrict__ part, float2* __restrict__ stats)
{
    int t = threadIdx.x;
    if (t < BB * GG) {
        float s = 0.f, q = 0.f;
        for (int i = 0; i < 32; ++i) { float2 p = part[t * 32 + i]; s += p.x; q += p.y; }
        const float invN = 1.0f / (float)(CPG * LL);
        float mean = s * invN;
        float var  = q * invN - mean * mean;
        stats[t] = make_float2(mean, rsqrtf(var + 1e-6f));
    }
}

// GroupNorm normalize + affine + TRANSPOSE: x [C,L] fp32 -> xnT [L,C] f16
__global__ __launch_bounds__(256) void gn_norm_t(
    const float* __restrict__ x, const float2* __restrict__ stats,
    const float* __restrict__ gw, const float* __restrict__ gb,
    f16* __restrict__ xnT)
{
    __shared__ float t[64][65];
    int l0 = blockIdx.x * 64, c0 = blockIdx.y * 64, b = blockIdx.z;
    float2 st = stats[b * GG + (c0 >> 7)];
    const float* xb = x + (size_t)b * CC * LL;
    for (int i = threadIdx.x; i < 4096; i += 256) {
        int c = i >> 6, l = i & 63;
        float v = xb[(size_t)(c0 + c) * LL + l0 + l];
        t[c][l] = (v - st.x) * st.y * gw[c0 + c] + gb[c0 + c];
    }
    __syncthreads();
    f16* o = xnT + (size_t)b * LL * CC;
    for (int i = threadIdx.x; i < 4096; i += 256) {
        int l = i >> 6, c = i & 63;
        o[(size_t)(l0 + l) * CC + c0 + c] = (f16)t[c][l];
    }
}

// ---------------------------------------------------------------------------
// Generic batched GEMM  C[M,N] = alpha * A[M,K] · B[N,K]^T (+bias)(+resid)
// All operands K-contiguous f16. 128x128 tile, BK=64, 4 waves (2x2), 4x4 frags.
// Staging: global_load_lds width=16, LINEAR LDS dest, INVERSE-swizzled global
// source (rule #21). Reads use physByte = (row*128 + colByte) ^ ((row&7)<<4).
// Fill order: linear byte o = it*4096 + wave*1024 + lane*16
//   -> row = it*32 + wave*8 + (lane>>3), row&7 = lane>>3
//   -> source col element = ((lane&7) ^ (lane>>3)) * 8   (constant per lane)
// ---------------------------------------------------------------------------
template<int BIAS_MODE, bool RESID, typename OUT_T>
__global__ __launch_bounds__(256) void gemm_bt(
    const f16* __restrict__ A, size_t sA,
    const f16* __restrict__ B, size_t sB,
    OUT_T* __restrict__ Co, size_t sC,
    const float* __restrict__ resid, size_t sR,
    const float* __restrict__ bias,
    int M, int N, int K, int lda, int ldb, int ldc, float alpha)
{
    const int tid  = threadIdx.x;
    const int lane = tid & 63;
    const int wave = tid >> 6;
    const int wr = wave >> 1, wc = wave & 1;
    const int l15 = lane & 15, lhi = lane >> 4;
    const int bm = blockIdx.y, bn = blockIdx.x, bz = blockIdx.z;

    A  += (size_t)bz * sA;
    B  += (size_t)bz * sB;
    Co += (size_t)bz * sC;

    __shared__ f16 ldsA[128 * 64];
    __shared__ f16 ldsB[128 * 64];

    f32x4 acc[4][4] = {};

    // staging source column (elements), inverse-swizzled; constant per lane
    const int srcColE = ((lane & 7) ^ (lane >> 3)) * 8;
    const int rowBase = wave * 8 + (lane >> 3);          // + it*32
    const f16* Ag = A + (size_t)(bm * 128 + rowBase) * lda + srcColE;
    const f16* Bg = B + (size_t)(bn * 128 + rowBase) * ldb + srcColE;

    for (int k0 = 0; k0 < K; k0 += 64) {
#pragma unroll
        for (int it = 0; it < 4; ++it) {
            f16* la = (f16*)((char*)ldsA + it * 4096 + wave * 1024);
            f16* lb = (f16*)((char*)ldsB + it * 4096 + wave * 1024);
            gload_lds16(Ag + (size_t)(it * 32) * lda + k0, la);
            gload_lds16(Bg + (size_t)(it * 32) * ldb + k0, lb);
        }
        __syncthreads();
#pragma unroll
        for (int kk = 0; kk < 64; kk += 32) {
            const int kb2 = (kk + lhi * 8) * 2;   // byte col of fragment
            f16x8 af[4], bfr[4];
#pragma unroll
            for (int m = 0; m < 4; ++m) {
                int row = wr * 64 + m * 16 + l15;
                int phys = ((row * 128 + kb2) ^ ((row & 7) << 4)) >> 1;
                af[m] = *(const f16x8*)(ldsA + phys);
            }
#pragma unroll
            for (int n = 0; n < 4; ++n) {
                int row = wc * 64 + n * 16 + l15;
                int phys = ((row * 128 + kb2) ^ ((row & 7) << 4)) >> 1;
                bfr[n] = *(const f16x8*)(ldsB + phys);
            }
#pragma unroll
            for (int m = 0; m < 4; ++m)
#pragma unroll
                for (int n = 0; n < 4; ++n)
                    acc[m][n] = __builtin_amdgcn_mfma_f32_16x16x32_f16(
                        af[m], bfr[n], acc[m][n], 0, 0, 0);
        }
        __syncthreads();
    }

#pragma unroll
    for (int m = 0; m < 4; ++m) {
#pragma unroll
        for (int n = 0; n < 4; ++n) {
            int col = bn * 128 + wc * 64 + n * 16 + l15;
#pragma unroll
            for (int r = 0; r < 4; ++r) {
                int row = bm * 128 + wr * 64 + m * 16 + lhi * 4 + r;
                float v = acc[m][n][r] * alpha;
                if (BIAS_MODE == 1) v += bias[row];
                if (BIAS_MODE == 2) v += bias[col];
                if (RESID) v += resid[(size_t)bz * sR + (size_t)row * ldc + col];
                Co[(size_t)row * ldc + col] = (OUT_T)v;
            }
        }
    }
}

// ---------------------------------------------------------------------------
// Row softmax in-place on f16 P [L, L] per (b, row). grid (LL, BB), block 256.
// ---------------------------------------------------------------------------
__global__ __launch_bounds__(256) void softmax_rows(f16* __restrict__ P)
{
    int i = blockIdx.x, b = blockIdx.y;
    f16* row = P + ((size_t)b * LL + (size_t)i) * LL;
    int tid = threadIdx.x;
    f16x8 v = ((const f16x8*)row)[tid];
    float f[8], mx = -1e30f;
#pragma unroll
    for (int j = 0; j < 8; ++j) { f[j] = (float)v[j]; mx = fmaxf(mx, f[j]); }
    for (int o = 32; o; o >>= 1) mx = fmaxf(mx, __shfl_xor(mx, o));
    __shared__ float red1[4];
    __shared__ float red2[4];
    int wave = tid >> 6, lane = tid & 63;
    if (lane == 0) red1[wave] = mx;
    __syncthreads();
    mx = fmaxf(fmaxf(red1[0], red1[1]), fmaxf(red1[2], red1[3]));
    float s = 0.f;
#pragma unroll
    for (int j = 0; j < 8; ++j) { f[j] = __expf(f[j] - mx); s += f[j]; }
    for (int o = 32; o; o >>= 1) s += __shfl_xor(s, o);
    if (lane == 0) red2[wave] = s;
    __syncthreads();
    s = red2[0] + red2[1] + red2[2] + red2[3];
    float inv = 1.0f / s;
    f16x8 o8;
#pragma unroll
    for (int j = 0; j < 8; ++j) o8[j] = (f16)(f[j] * inv);
    ((f16x8*)row)[tid] = o8;
}

// Fallback marker if workspace is too small (distinct absmax signal ~12345)
__global__ void fill_marker(float* out, int n)
{
    int i = blockIdx.x * 256 + threadIdx.x;
    if (i < n) out[i] = 12345.0f;
}

// ---------------------------------------------------------------------------
extern "C" void kernel_launch(void* const* d_in, const int* in_sizes, int n_in,
                              void* d_out, int out_size, void* d_ws, size_t ws_size,
                              hipStream_t stream)
{
    const float* x  = (const float*)d_in[0];
    const float* gw = (const float*)d_in[1];
    const float* gb = (const float*)d_in[2];
    const float* qw = (const float*)d_in[3];
    const float* qb = (const float*)d_in[4];
    const float* kw = (const float*)d_in[5];
    const float* kb = (const float*)d_in[6];
    const float* vw = (const float*)d_in[7];
    const float* vb = (const float*)d_in[8];
    const float* pw = (const float*)d_in[9];
    const float* pb = (const float*)d_in[10];
    float* out = (float*)d_out;

    // workspace layout (bytes)
    char* w = (char*)d_ws;
    float2* part  = (float2*)w;                       //   8 KB
    float2* stats = (float2*)(w + 8192);              //   256 B
    f16* Wqk  = (f16*)(w + 16384);                    //   1 MB   [1024,512]
    f16* Wv   = Wqk + (size_t)1024 * CC;              // 512 KB   [512,512]
    f16* Wp   = Wv  + (size_t)CC * CC;                // 512 KB
    float* qkb = (float*)(Wp + (size_t)CC * CC);      //   4 KB
    f16* xnT  = (f16*)((char*)qkb + 4096);            // 16 MB    [B][L,C]
    f16* QK   = xnT + (size_t)BB * LL * CC;           // 32 MB    [B][L,1024]
    f16* Vm   = QK  + (size_t)BB * LL * 1024;         // 16 MB    [B][C,L]
    f16* Pm   = Vm  + (size_t)BB * CC * LL;           // 64 MB    [B][L,L]
    f16* O2   = xnT;  // alias: xnT dead after gemm2  //          [B][L,C]
    size_t need = (size_t)((char*)(Pm + (size_t)BB * LL * LL) - w);
    if (ws_size < need) {
        fill_marker<<<(out_size + 255) / 256, 256, 0, stream>>>(out, out_size);
        return;
    }

    convert_w<<<dim3((CC * CC + 255) / 256), 256, 0, stream>>>(
        qw, kw, vw, pw, qb, kb, Wqk, Wv, Wp, qkb);
    gn_partial<<<dim3(32, GG, BB), 256, 0, stream>>>(x, part);
    gn_finalize<<<1, 64, 0, stream>>>(part, stats);
    gn_norm_t<<<dim3(LL / 64, CC / 64, BB), 256, 0, stream>>>(x, stats, gw, gb, xnT);

    // GEMM1: [Q|K]t[l, n] = xnT[l,:] . Wqk[n,:] + qkb[n]     (M=L, N=1024, K=C)
    gemm_bt<2, false, f16><<<dim3(1024 / 128, LL / 128, BB), 256, 0, stream>>>(
        xnT, (size_t)LL * CC, Wqk, 0, QK, (size_t)LL * 1024, nullptr, 0, qkb,
        LL, 1024, CC, CC, CC, 1024, 1.0f);

    // GEMM2: V[c, l] = Wv[c,:] . xnT[l,:] + vb[c]            (M=C, N=L, K=C)
    gemm_bt<1, false, f16><<<dim3(LL / 128, CC / 128, BB), 256, 0, stream>>>(
        Wv, 0, xnT, (size_t)LL * CC, Vm, (size_t)CC * LL, nullptr, 0, vb,
        CC, LL, CC, CC, CC, LL, 1.0f);

    // GEMM3: S[i, j] = scale * Qt[i,:] . Kt[j,:]             (M=L, N=L, K=C)
    gemm_bt<0, false, f16><<<dim3(LL / 128, LL / 128, BB), 256, 0, stream>>>(
        QK, (size_t)LL * 1024, QK + CC, (size_t)LL * 1024, Pm, (size_t)LL * LL,
        nullptr, 0, nullptr,
        LL, LL, CC, 1024, 1024, LL, 0.04419417382415922f);

    softmax_rows<<<dim3(LL, BB), 256, 0, stream>>>(Pm);

    // GEMM4: O2[i, c] = P[i,:] . V[c,:]                      (M=L, N=C, K=L)
    gemm_bt<0, false, f16><<<dim3(CC / 128, LL / 128, BB), 256, 0, stream>>>(
        Pm, (size_t)LL * LL, Vm, (size_t)CC * LL, O2, (size_t)LL * CC,
        nullptr, 0, nullptr,
        LL, CC, LL, LL, LL, CC, 1.0f);

    // GEMM5: out[c, l] = Wp[c,:] . O2[l,:] + pb[c] + x[c,l]  (M=C, N=L, K=C)
    gemm_bt<1, true, float><<<dim3(LL / 128, CC / 128, BB), 256, 0, stream>>>(
        Wp, 0, O2, (size_t)LL * CC, out, (size_t)CC * LL, x, (size_t)CC * LL, pb,
        CC, LL, CC, CC, CC, LL, 1.0f);
}